// Round 1
// baseline (158.280 us; speedup 1.0000x reference)
//
#include <hip/hip_runtime.h>

#define KK 121           // kernel_size^2 = 11*11
#define OUT_CH 512
#define IN_CH 512
#define NPAIR (OUT_CH * IN_CH)
#define NOUT (NPAIR * KK)       // 31,719,424 floats
#define NVEC (NOUT / 4)         // 7,929,856 float4 stores (exact)

__global__ __launch_bounds__(256) void
quad_multi2d_kernel(const float* __restrict__ chol,
                    const float* __restrict__ pg,
                    float* __restrict__ out) {
    __shared__ float s_x1[KK];
    __shared__ float s_x2[KK];
    {
        int t = threadIdx.x;
        if (t < KK) {
            s_x1[t] = pg[t];
            s_x2[t] = pg[KK + t];
        }
    }
    __syncthreads();

    int tid = blockIdx.x * blockDim.x + threadIdx.x;   // < 7.93M, fits int
    if (tid >= NVEC) return;

    int e0   = tid * 4;            // first output element this thread owns
    int pair = e0 / KK;            // compiler emits magic-mul division
    int kp   = e0 - pair * KK;

    // chol_raw[pair] = {a00, a01, a10, a11}; L = [[exp(a00),0],[a10,exp(a11)]]
    float4 cp  = ((const float4*)chol)[pair];
    float  e1  = __expf(-cp.x);    // 1/l11
    float  l21 = cp.z;
    float  e2  = __expf(-cp.w);    // 1/l22

    float r[4];
#pragma unroll
    for (int j = 0; j < 4; ++j) {
        if (kp == KK) {            // straddle a pair boundary (≤ once/thread)
            kp = 0;
            ++pair;
            cp  = ((const float4*)chol)[pair];
            e1  = __expf(-cp.x);
            l21 = cp.z;
            e2  = __expf(-cp.w);
        }
        float b1 = s_x1[kp] * e1;
        float b2 = (s_x2[kp] - l21 * b1) * e2;
        r[j] = b1 * b1 + b2 * b2;
        ++kp;
    }

    float4 o;
    o.x = r[0]; o.y = r[1]; o.z = r[2]; o.w = r[3];
    ((float4*)out)[tid] = o;
}

extern "C" void kernel_launch(void* const* d_in, const int* in_sizes, int n_in,
                              void* d_out, int out_size, void* d_ws, size_t ws_size,
                              hipStream_t stream) {
    const float* chol = (const float*)d_in[0];   // (512,512,2,2) fp32
    const float* pg   = (const float*)d_in[1];   // (2,121) fp32
    float* out        = (float*)d_out;           // (512,512,11,11) fp32

    const int block = 256;
    const int grid  = (NVEC + block - 1) / block;  // 30,976 exactly
    quad_multi2d_kernel<<<grid, block, 0, stream>>>(chol, pg, out);
}

// Round 2
// 136.080 us; speedup vs baseline: 1.1631x; 1.1631x over previous
//
#include <hip/hip_runtime.h>

#define KK 121                  // 11*11
#define NPAIR (512 * 512)       // 262,144 (o,i) pairs
#define NOUT (NPAIR * KK)       // 31,719,424 floats
#define NVEC (NOUT / 4)         // 7,929,856 float4 stores (exact)
#define WSREQ ((size_t)(NPAIR + 1) * 16)   // padded param table

// ---------- pass 1: per-pair params: {e1=exp(-a00), f=l21*e2, e2=exp(-a11)} ----------
__global__ __launch_bounds__(256) void
prep_params_kernel(const float* __restrict__ chol, float4* __restrict__ q) {
    int tid = blockIdx.x * 256 + threadIdx.x;
    if (tid < NPAIR) {
        float4 c = ((const float4*)chol)[tid];   // {a00, a01, a10, a11}
        float e1 = __expf(-c.x);
        float e2 = __expf(-c.w);
        float4 o;
        o.x = e1; o.y = c.z * e2; o.z = e2; o.w = 0.f;
        q[tid] = o;
    } else if (tid == NPAIR) {                   // pad entry so pair+1 never OOB
        q[tid] = make_float4(0.f, 0.f, 0.f, 0.f);
    }
}

// ---------- pass 2: main write kernel ----------
// 8x-replicated position tables, replica stride 129 floats (129 % 32 == 1 bank).
// Lane uses replica (lane>>3): bank = (base + 4*(lane&7) + (lane>>3)) % 32
// -> near-uniform 2-way access, conflict-free (m136).
__global__ __launch_bounds__(256) void
quad_main_kernel(const float4* __restrict__ q, const float* __restrict__ pg,
                 float4* __restrict__ out) {
    __shared__ float sx1[8 * 129];
    __shared__ float sx2[8 * 129];
    int t = threadIdx.x;
    if (t < KK) {
        float a = pg[t], b = pg[KK + t];
#pragma unroll
        for (int r = 0; r < 8; ++r) { sx1[r * 129 + t] = a; sx2[r * 129 + t] = b; }
    }
    __syncthreads();

    int tid  = blockIdx.x * 256 + t;
    int e0   = tid * 4;
    int pair = e0 / KK;            // magic-mul division
    int kp0  = e0 - pair * KK;

    float4 q0 = q[pair];
    float4 q1 = q[pair + 1];       // ws is padded; always in-bounds
    int rb = ((t & 63) >> 3) * 129;

    float res[4];
#pragma unroll
    for (int j = 0; j < 4; ++j) {
        int  kp = kp0 + j;
        bool w  = kp >= KK;        // at most one wrap per thread
        kp = w ? kp - KK : kp;
        float e1 = w ? q1.x : q0.x;
        float f  = w ? q1.y : q0.y;
        float e2 = w ? q1.z : q0.z;
        float x1 = sx1[rb + kp];
        float x2 = sx2[rb + kp];
        float b1 = x1 * e1;
        float b2 = fmaf(-f, b1, x2 * e2);
        res[j] = fmaf(b2, b2, b1 * b1);
    }
    float4 o;
    o.x = res[0]; o.y = res[1]; o.z = res[2]; o.w = res[3];
    out[tid] = o;
}

// ---------- fallback: fused single pass (if ws too small) ----------
__global__ __launch_bounds__(256) void
quad_fused_kernel(const float* __restrict__ chol, const float* __restrict__ pg,
                  float* __restrict__ out) {
    __shared__ float sx1[8 * 129];
    __shared__ float sx2[8 * 129];
    int t = threadIdx.x;
    if (t < KK) {
        float a = pg[t], b = pg[KK + t];
#pragma unroll
        for (int r = 0; r < 8; ++r) { sx1[r * 129 + t] = a; sx2[r * 129 + t] = b; }
    }
    __syncthreads();

    int tid  = blockIdx.x * 256 + t;
    int e0   = tid * 4;
    int pair = e0 / KK;
    int kp0  = e0 - pair * KK;
    int pairB = pair + 1 < NPAIR ? pair + 1 : NPAIR - 1;

    float4 cA = ((const float4*)chol)[pair];
    float4 cB = ((const float4*)chol)[pairB];
    float e1A = __expf(-cA.x), e2A = __expf(-cA.w), fA = cA.z * e2A;
    float e1B = __expf(-cB.x), e2B = __expf(-cB.w), fB = cB.z * e2B;
    int rb = ((t & 63) >> 3) * 129;

    float res[4];
#pragma unroll
    for (int j = 0; j < 4; ++j) {
        int  kp = kp0 + j;
        bool w  = kp >= KK;
        kp = w ? kp - KK : kp;
        float e1 = w ? e1B : e1A;
        float f  = w ? fB  : fA;
        float e2 = w ? e2B : e2A;
        float x1 = sx1[rb + kp];
        float x2 = sx2[rb + kp];
        float b1 = x1 * e1;
        float b2 = fmaf(-f, b1, x2 * e2);
        res[j] = fmaf(b2, b2, b1 * b1);
    }
    float4 o;
    o.x = res[0]; o.y = res[1]; o.z = res[2]; o.w = res[3];
    ((float4*)out)[tid] = o;
}

extern "C" void kernel_launch(void* const* d_in, const int* in_sizes, int n_in,
                              void* d_out, int out_size, void* d_ws, size_t ws_size,
                              hipStream_t stream) {
    const float* chol = (const float*)d_in[0];   // (512,512,2,2) fp32
    const float* pg   = (const float*)d_in[1];   // (2,121) fp32
    float* out        = (float*)d_out;           // (512,512,11,11) fp32

    const int block = 256;
    const int gridMain = NVEC / block;           // 30,976 exactly

    if (ws_size >= WSREQ) {
        float4* q = (float4*)d_ws;
        const int gridPrep = (NPAIR + 1 + block - 1) / block;   // 1025
        prep_params_kernel<<<gridPrep, block, 0, stream>>>(chol, q);
        quad_main_kernel<<<gridMain, block, 0, stream>>>(q, pg, (float4*)out);
    } else {
        quad_fused_kernel<<<gridMain, block, 0, stream>>>(chol, pg, out);
    }
}

// Round 3
// 131.619 us; speedup vs baseline: 1.2026x; 1.0339x over previous
//
#include <hip/hip_runtime.h>

#define KK 121                   // 11*11
#define NPAIR (512 * 512)        // 262,144 (o,i) pairs
#define PPB 64                   // pairs per block
#define NBLK (NPAIR / PPB)       // 4096 blocks
#define STAGE_F4 (PPB * KK / 4)  // 1936 float4 per block (exact)

// out[p][k] = P_p*x1[k]^2 + Q_p*x2[k]^2 + R_p*x1[k]*x2[k]
//   e1 = exp(-a00), e2 = exp(-a11), f = a10*e2
//   P = e1^2*(1+f^2), Q = e2^2, R = -2*f*e1*e2
__global__ __launch_bounds__(256) void
quad_rank3_kernel(const float4* __restrict__ chol4,
                  const float* __restrict__ pg,
                  float4* __restrict__ out4) {
    __shared__ float4 s_uvw[KK];                    // {x1^2, x2^2, x1*x2, 0}
    __shared__ __align__(16) float stage[PPB * KK]; // 30,976 B

    const int t = threadIdx.x;

    if (t < KK) {
        float x1 = pg[t];
        float x2 = pg[KK + t];
        float4 g;
        g.x = x1 * x1; g.y = x2 * x2; g.z = x1 * x2; g.w = 0.f;
        s_uvw[t] = g;
    }

    const int p       = t & 63;         // pair within block
    const int quarter = t >> 6;         // 0..3 -> kp ranges 31,30,30,30
    const int k0 = (quarter == 0) ? 0 : (30 * quarter + 1);
    const int k1 = (quarter == 0) ? 31 : (k0 + 30);

    // per-pair params (4 threads/pair duplicate this tiny bit of work)
    float4 c = chol4[blockIdx.x * PPB + p];   // {a00,a01,a10,a11}
    float e1 = __expf(-c.x);
    float e2 = __expf(-c.w);
    float f  = c.z * e2;
    float P  = e1 * e1 * fmaf(f, f, 1.f);
    float Q  = e2 * e2;
    float R  = -2.f * f * e1 * e2;

    __syncthreads();

    float* st = &stage[p * KK];
#pragma unroll 5
    for (int k = k0; k < k1; ++k) {
        float4 g = s_uvw[k];                       // broadcast read
        st[k] = fmaf(P, g.x, fmaf(Q, g.y, R * g.z));
    }

    __syncthreads();

    // coalesced staged write-out: 1936 float4, contiguous & 16B-aligned
    const float4* s4 = (const float4*)stage;
    float4* o = out4 + (size_t)blockIdx.x * STAGE_F4;
#pragma unroll
    for (int i = t; i < STAGE_F4; i += 256) {
        o[i] = s4[i];
    }
}

extern "C" void kernel_launch(void* const* d_in, const int* in_sizes, int n_in,
                              void* d_out, int out_size, void* d_ws, size_t ws_size,
                              hipStream_t stream) {
    const float4* chol4 = (const float4*)d_in[0];  // (512,512,2,2) fp32
    const float* pg     = (const float*)d_in[1];   // (2,121) fp32
    float4* out4        = (float4*)d_out;          // (512,512,11,11) fp32

    quad_rank3_kernel<<<NBLK, 256, 0, stream>>>(chol4, pg, out4);
}